// Round 4
// baseline (2566.693 us; speedup 1.0000x reference)
//
#include <hip/hip_runtime.h>
#include <hip/hip_bf16.h>

#define NPAD 16640
#define TOK  16385
#define CDIM 512
#define NHEAD 8
#define DHEAD 64
#define NLAND 256
#define LFAC  65
#define PAD0  255
#define NCHUNK 65   // chunks of 256 rows: 65*256 = 16640

typedef __attribute__((ext_vector_type(8))) short sh8;
typedef __attribute__((ext_vector_type(4))) float f4;

__device__ __forceinline__ float wave_sum(float v){
  #pragma unroll
  for(int o=32;o;o>>=1) v += __shfl_xor(v,o);
  return v;
}
__device__ __forceinline__ float wave_max(float v){
  #pragma unroll
  for(int o=32;o;o>>=1) v = fmaxf(v, __shfl_xor(v,o));
  return v;
}

// bf16 RNE pack helpers
__device__ __forceinline__ unsigned bfbits(float x){
  unsigned u = __float_as_uint(x);
  return (u + 0x7fffu + ((u >> 16) & 1u)) >> 16;
}
__device__ __forceinline__ sh8 pack8f(float4 a, float4 b){
  sh8 r;
  r[0]=(short)bfbits(a.x); r[1]=(short)bfbits(a.y); r[2]=(short)bfbits(a.z); r[3]=(short)bfbits(a.w);
  r[4]=(short)bfbits(b.x); r[5]=(short)bfbits(b.y); r[6]=(short)bfbits(b.z); r[7]=(short)bfbits(b.w);
  return r;
}
#define MFMA16(a,b,c) __builtin_amdgcn_mfma_f32_16x16x32_bf16(a,b,c,0,0,0)

// ---------------- row copy (cls token) ----------------
__global__ void k_copyrow(float* dst, const float* __restrict__ src){
  dst[threadIdx.x] = src[threadIdx.x];
}

// ---------------- layernorm + front pad ----------------
__global__ __launch_bounds__(256) void k_ln_pad(const float* __restrict__ A,
    const float* __restrict__ g, const float* __restrict__ b, float* __restrict__ B){
  int w = threadIdx.x >> 6, lane = threadIdx.x & 63;
  int row = blockIdx.x*4 + w;
  float* out = B + (size_t)row*CDIM;
  if(row < PAD0){
    #pragma unroll
    for(int i=0;i<8;i++) out[lane + i*64] = 0.f;
    return;
  }
  const float* x = A + (size_t)(row-PAD0)*CDIM;
  int c0 = lane*4, c1 = 256 + lane*4;
  float4 v0 = *(const float4*)(x + c0);
  float4 v1 = *(const float4*)(x + c1);
  float xs[8] = {v0.x,v0.y,v0.z,v0.w,v1.x,v1.y,v1.z,v1.w};
  float s = 0;
  #pragma unroll
  for(int i=0;i<8;i++) s += xs[i];
  s = wave_sum(s);
  float mu = s * (1.f/512.f);
  float vs = 0;
  #pragma unroll
  for(int i=0;i<8;i++){ float d = xs[i]-mu; vs += d*d; }
  vs = wave_sum(vs) * (1.f/512.f);
  float rs = rsqrtf(vs + 1e-5f);
  float4 g0 = *(const float4*)(g + c0); float4 g1 = *(const float4*)(g + c1);
  float4 b0 = *(const float4*)(b + c0); float4 b1 = *(const float4*)(b + c1);
  float4 o0, o1;
  o0.x = (xs[0]-mu)*rs*g0.x + b0.x; o0.y = (xs[1]-mu)*rs*g0.y + b0.y;
  o0.z = (xs[2]-mu)*rs*g0.z + b0.z; o0.w = (xs[3]-mu)*rs*g0.w + b0.w;
  o1.x = (xs[4]-mu)*rs*g1.x + b1.x; o1.y = (xs[5]-mu)*rs*g1.y + b1.y;
  o1.z = (xs[6]-mu)*rs*g1.z + b1.z; o1.w = (xs[7]-mu)*rs*g1.w + b1.w;
  *(float4*)(out + c0) = o0;
  *(float4*)(out + c1) = o1;
}

// ---------------- MFMA GEMM: C[M,N] = A[M,K] @ WT[N,K]^T, bf16 inputs ----------------
template<int MODE>
__global__ __launch_bounds__(256) void k_gemm_mfma(const float* __restrict__ A, int lda,
    const float* __restrict__ WT, int K, const float* __restrict__ bias,
    float* out0, float* out1, float* out2, int M){
  __shared__ short As[128*32];
  __shared__ short Bs[128*32];
  int t = threadIdx.x, lane = t & 63, wv = t >> 6, g = lane >> 4, l15 = lane & 15;
  int row0 = blockIdx.y*128, n0 = blockIdx.x*128;
  int wm = (wv>>1)*64, wn = (wv&1)*64;
  f4 acc[4][4] = {};
  for(int k0 = 0; k0 < K; k0 += 32){
    #pragma unroll
    for(int u=0; u<2; u++){
      int gi = t + u*256;               // 512 granules of 8 elems
      int m = gi >> 2, kb = (gi & 3) * 8;
      float4 va = make_float4(0,0,0,0), vb = make_float4(0,0,0,0);
      int gr = row0 + m;
      if(gr < M){
        va = *(const float4*)(A + (size_t)gr*lda + k0 + kb);
        vb = *(const float4*)(A + (size_t)gr*lda + k0 + kb + 4);
      }
      int swz = (((m&3) ^ ((m>>2)&3)) << 4);
      *(sh8*)((char*)As + m*64 + ((kb*2) ^ swz)) = pack8f(va, vb);
      float4 wa = *(const float4*)(WT + (size_t)(n0+m)*K + k0 + kb);
      float4 wb = *(const float4*)(WT + (size_t)(n0+m)*K + k0 + kb + 4);
      *(sh8*)((char*)Bs + m*64 + ((kb*2) ^ swz)) = pack8f(wa, wb);
    }
    __syncthreads();
    sh8 af[4], bf[4];
    #pragma unroll
    for(int mt=0; mt<4; mt++){
      int r = wm + mt*16 + l15;
      af[mt] = *(sh8*)((char*)As + r*64 + ((g*16) ^ (((r&3)^((r>>2)&3))<<4)));
    }
    #pragma unroll
    for(int nt=0; nt<4; nt++){
      int r = wn + nt*16 + l15;
      bf[nt] = *(sh8*)((char*)Bs + r*64 + ((g*16) ^ (((r&3)^((r>>2)&3))<<4)));
    }
    #pragma unroll
    for(int mt=0; mt<4; mt++)
      #pragma unroll
      for(int nt=0; nt<4; nt++)
        acc[mt][nt] = MFMA16(af[mt], bf[nt], acc[mt][nt]);
    __syncthreads();
  }
  #pragma unroll
  for(int mt=0; mt<4; mt++){
    #pragma unroll
    for(int r=0; r<4; r++){
      int gm = row0 + wm + mt*16 + g*4 + r;
      if(gm >= M) continue;
      #pragma unroll
      for(int nt=0; nt<4; nt++){
        int gn = n0 + wn + nt*16 + l15;
        float v = acc[mt][nt][r];
        if(MODE == 0){
          v += bias[gn];
          out0[(size_t)gm*CDIM + gn] = v > 0.f ? v : 0.f;
        } else if(MODE == 1){
          int p = gn >> 9, rr = gn & 511;
          int hh = rr >> 6, dd = rr & 63;
          if(p == 0) v *= 0.125f;
          float* dst = (p==0) ? out0 : (p==1 ? out1 : out2);
          dst[((size_t)hh*NPAD + gm)*DHEAD + dd] = v;
        } else {
          out0[(size_t)gm*CDIM + gn] += v + bias[gn];
        }
      }
    }
  }
}

// ---------------- landmark means ----------------
__global__ void k_landmark(const float* __restrict__ src, float* __restrict__ dst){
  int bidx = blockIdx.x;               // h*256 + m
  int h = bidx >> 8, m = bidx & 255, d = threadIdx.x;
  const float* p = src + ((size_t)h*NPAD + (size_t)m*LFAC)*DHEAD + d;
  float s = 0;
  for(int j=0;j<LFAC;j++) s += p[(size_t)j*DHEAD];
  dst[(size_t)bidx*DHEAD + d] = s * (1.f/LFAC);
}

// ---------------- a2 = softmax(ql @ kl^T) ----------------
__global__ __launch_bounds__(256) void k_a2(const float* __restrict__ ql,
    const float* __restrict__ kl, float* __restrict__ a2){
  __shared__ __hip_bfloat16 klt[64*256];  // [d][m]
  int h = blockIdx.y;
  int t = threadIdx.x;
  const float* klh = kl + (size_t)h*NLAND*DHEAD;
  for(int r=0;r<64;r++){
    int idx = r*256 + t;
    int d = idx >> 8, m = idx & 255;
    klt[idx] = __float2bfloat16(klh[m*DHEAD + d]);
  }
  __syncthreads();
  int w = t >> 6, lane = t & 63;
  const float* qlh = ql + (size_t)h*NLAND*DHEAD;
  for(int rr=0; rr<16; rr++){
    int m = blockIdx.x*64 + w*16 + rr;
    const float* q = qlh + (size_t)m*DHEAD;
    float s[4] = {0,0,0,0};
    #pragma unroll
    for(int d=0; d<64; d++){
      float qv = q[d];
      #pragma unroll
      for(int qd=0; qd<4; qd++)
        s[qd] += qv * __bfloat162float(klt[d*256 + qd*64 + lane]);
    }
    float e[4], den = 0.f;
    #pragma unroll
    for(int qd=0; qd<4; qd++){ e[qd] = __expf(s[qd]); den += e[qd]; }
    den = wave_sum(den);
    float inv = 1.f/den;
    float* arow = a2 + ((size_t)h*NLAND + m)*NLAND;
    #pragma unroll
    for(int qd=0; qd<4; qd++) arow[qd*64 + lane] = e[qd]*inv;
  }
}

// ---------------- pinv init ----------------
__global__ void k_colmax(const float* __restrict__ a2, float* __restrict__ hmax){
  __shared__ float red[4];
  int h = blockIdx.x, t = threadIdx.x;
  const float* p = a2 + (size_t)h*65536 + t;
  float s = 0;
  for(int m=0;m<256;m++) s += p[(size_t)m*256];
  float mx = wave_max(s);
  if((t & 63) == 0) red[t>>6] = mx;
  __syncthreads();
  if(t == 0) hmax[h] = fmaxf(fmaxf(red[0],red[1]), fmaxf(red[2],red[3]));
}
__global__ void k_scal(const float* __restrict__ hmax, float* __restrict__ scal){
  int t = threadIdx.x;
  float v = (t < 8) ? hmax[t] : -1e30f;
  v = wave_max(v);
  if(t == 0) scal[0] = v;
}
__global__ void k_zinit(const float* __restrict__ a2, const float* __restrict__ scal,
                        float* __restrict__ z){
  int h = blockIdx.y;
  int idx = blockIdx.x*256 + threadIdx.x;
  int m = idx >> 8, j = idx & 255;
  z[(size_t)h*65536 + idx] = a2[(size_t)h*65536 + (size_t)j*256 + m] / scal[0];
}

// ---------------- grid barrier (device-scope, monotonic counter) ----------------
__device__ __forceinline__ void gbar(unsigned* bar, unsigned tgt){
  __syncthreads();
  if(threadIdx.x == 0){
    __threadfence();
    atomicAdd(bar, 1u);
    while(__hip_atomic_load(bar, __ATOMIC_RELAXED, __HIP_MEMORY_SCOPE_AGENT) < tgt)
      __builtin_amdgcn_s_sleep(2);
    __threadfence();
  }
  __syncthreads();
}

// ---------------- fused pinv: 6 Newton iters, 4 GEMM stages each ----------------
// 256 blocks: head = bid>>5, tile = bid&31 -> m-tile (8 x 32 rows) x n-tile (4 x 64 cols)
template<bool TRANS>
__device__ __forceinline__ void tile_gemm(const float* __restrict__ A,
    const float* __restrict__ B, float* __restrict__ C,
    int m0, int n0, float alpha, float beta,
    float (*As)[36], float (*Bs)[68]){
  int t = threadIdx.x, tx = t & 15, ty = t >> 4;
  float acc[2][4] = {};
  for(int k0=0; k0<256; k0+=32){
    {
      int r = t >> 3, cb = (t & 7) * 4;
      float4 va = *(const float4*)(A + (size_t)(m0+r)*256 + k0 + cb);
      As[cb+0][r]=va.x; As[cb+1][r]=va.y; As[cb+2][r]=va.z; As[cb+3][r]=va.w;
    }
    #pragma unroll
    for(int u=0;u<2;u++){
      int idx = t + u*256;
      int kr = idx >> 4, nb = (idx & 15) * 4;
      float4 w = *(const float4*)(B + (size_t)(k0+kr)*256 + n0 + nb);
      if(TRANS){
        int gk = k0+kr, gn = n0+nb;
        w.x = ((gk==gn+0)?alpha:0.f) - w.x;
        w.y = ((gk==gn+1)?alpha:0.f) - w.y;
        w.z = ((gk==gn+2)?alpha:0.f) - w.z;
        w.w = ((gk==gn+3)?alpha:0.f) - w.w;
      }
      *(float4*)&Bs[kr][nb] = w;
    }
    __syncthreads();
    #pragma unroll
    for(int k=0;k<32;k++){
      float a0 = As[k][ty*2], a1 = As[k][ty*2+1];
      float b[4]; *(float4*)b = *(const float4*)&Bs[k][tx*4];
      #pragma unroll
      for(int j=0;j<4;j++){ acc[0][j] += a0*b[j]; acc[1][j] += a1*b[j]; }
    }
    __syncthreads();
  }
  #pragma unroll
  for(int i=0;i<2;i++)
    #pragma unroll
    for(int j=0;j<4;j++)
      C[(size_t)(m0+ty*2+i)*256 + n0 + tx*4 + j] = acc[i][j]*beta;
}

__global__ __launch_bounds__(256) void k_pinv(const float* __restrict__ a2,
    float* __restrict__ z0, float* __restrict__ z1,
    float* __restrict__ X, float* __restrict__ T, float* __restrict__ U,
    unsigned* __restrict__ bar){
  __shared__ float As[32][36];
  __shared__ float Bs[32][68];
  int bid = blockIdx.x;
  int h = bid >> 5, tile = bid & 31;
  int m0 = (tile >> 2) * 32, n0 = (tile & 3) * 64;
  size_t off = (size_t)h * 65536;
  const float* a2h = a2 + off;
  float* zc = z0 + off; float* zn = z1 + off;
  float* Xh = X + off; float* Th = T + off; float* Uh = U + off;
  unsigned tgt = 0;
  for(int it=0; it<6; it++){
    tile_gemm<false>(a2h, zc, Xh, m0, n0, 0.f, 1.f, As, Bs);
    tgt += 256; gbar(bar, tgt);
    tile_gemm<true >(Xh, Xh, Th, m0, n0, 7.f, 1.f, As, Bs);
    tgt += 256; gbar(bar, tgt);
    tile_gemm<true >(Xh, Th, Uh, m0, n0, 15.f, 1.f, As, Bs);
    tgt += 256; gbar(bar, tgt);
    tile_gemm<true >(zc, Uh, zn, m0, n0, 13.f, 0.25f, As, Bs);
    float* tmp = zc; zc = zn; zn = tmp;
    if(it < 5){ tgt += 256; gbar(bar, tgt); }
  }
}

// ---------------- batched f32 GEMM 64x64 tile (used for w2^T) ----------------
template<int TRANS, int OUTT>
__global__ __launch_bounds__(256) void k_sgemm2(const float* __restrict__ A,
    const float* __restrict__ B, float* __restrict__ C,
    int M, int N, int K, long sA, long sB, long sC, float alpha, float beta){
  __shared__ float As[32][68];
  __shared__ float Bs[32][68];
  int bh = blockIdx.z;
  const float* Ah = A + (size_t)bh*sA;
  const float* Bh = B + (size_t)bh*sB;
  float* Ch = C + (size_t)bh*sC;
  int m0 = blockIdx.y*64, n0 = blockIdx.x*64;
  int t = threadIdx.x, tx = t & 15, ty = t >> 4;
  float acc[4][4] = {};
  for(int k0=0; k0<K; k0+=32){
    #pragma unroll
    for(int u=0; u<2; u++){
      int idx = t + u*256;
      int r = idx >> 3, cb = (idx & 7) * 4;
      float4 va = *(const float4*)(Ah + (size_t)(m0+r)*K + k0 + cb);
      As[cb+0][r]=va.x; As[cb+1][r]=va.y; As[cb+2][r]=va.z; As[cb+3][r]=va.w;
      int kr = idx >> 4, nb = (idx & 15) * 4;
      float4 w = *(const float4*)(Bh + (size_t)(k0+kr)*N + n0 + nb);
      if(TRANS){
        int gk = k0 + kr;
        w.x = ((gk==n0+nb+0)?alpha:0.f) - w.x;
        w.y = ((gk==n0+nb+1)?alpha:0.f) - w.y;
        w.z = ((gk==n0+nb+2)?alpha:0.f) - w.z;
        w.w = ((gk==n0+nb+3)?alpha:0.f) - w.w;
      }
      *(float4*)&Bs[kr][nb] = w;
    }
    __syncthreads();
    #pragma unroll
    for(int k=0;k<32;k++){
      float a[4], b[4];
      *(float4*)a = *(const float4*)&As[k][ty*4];
      *(float4*)b = *(const float4*)&Bs[k][tx*4];
      #pragma unroll
      for(int i=0;i<4;i++)
        #pragma unroll
        for(int j=0;j<4;j++) acc[i][j] += a[i]*b[j];
    }
    __syncthreads();
  }
  #pragma unroll
  for(int i=0;i<4;i++){
    #pragma unroll
    for(int j=0;j<4;j++){
      int gm = m0 + ty*4 + i, gn = n0 + tx*4 + j;
      float v = acc[i][j] * beta;
      if(OUTT) Ch[(size_t)gn*M + gm] = v;
      else     Ch[(size_t)gm*N + gn] = v;
    }
  }
}

// ---------------- MFMA flash a1 ----------------
__global__ __launch_bounds__(256) void k_a1_mfma(const float* __restrict__ Qb,
    const float* __restrict__ kl, const float* __restrict__ w2t, float* __restrict__ F){
  __shared__ short klL[128*64];
  __shared__ short w2L[64*128];
  __shared__ short pL[4][16*128];
  int h = blockIdx.y, n0 = blockIdx.x*128;
  int t = threadIdx.x, lane = t & 63, wv = t >> 6, g = lane >> 4, l15 = lane & 15;
  const float* klh = kl + (size_t)h*NLAND*DHEAD;
  const float* w2h = w2t + (size_t)h*DHEAD*NLAND;
  const float* qbase = Qb + (size_t)h*NPAD*DHEAD;
  sh8 aQ[2][2];
  #pragma unroll
  for(int st=0; st<2; st++)
    #pragma unroll
    for(int kk=0; kk<2; kk++){
      const float* p = qbase + (size_t)(n0 + wv*32 + st*16 + l15)*DHEAD + kk*32 + g*8;
      aQ[st][kk] = pack8f(*(const float4*)p, *(const float4*)(p+4));
    }
  f4 accO[2][4] = {};
  float den[2][4] = {};
  short* pw = pL[wv];
  for(int half=0; half<2; half++){
    __syncthreads();
    #pragma unroll
    for(int it=0; it<4; it++){
      int gi = t + it*256;
      int m = gi >> 3, db = (gi & 7) * 8;
      const float* p = klh + (size_t)(half*128 + m)*DHEAD + db;
      *(sh8*)((char*)klL + m*128 + ((db*2) ^ ((m&7)<<4))) =
          pack8f(*(const float4*)p, *(const float4*)(p+4));
      int d = gi >> 4, mb = (gi & 15) * 8;
      const float* p2 = w2h + (size_t)d*NLAND + half*128 + mb;
      *(sh8*)((char*)w2L + d*256 + ((mb*2) ^ ((d&7)<<4))) =
          pack8f(*(const float4*)p2, *(const float4*)(p2+4));
    }
    __syncthreads();
    #pragma unroll
    for(int st=0; st<2; st++){
      #pragma unroll
      for(int mt=0; mt<8; mt++){
        f4 s = {};
        #pragma unroll
        for(int kk=0; kk<2; kk++){
          int m = mt*16 + l15;
          sh8 b = *(sh8*)((char*)klL + m*128 + ((kk*64 + g*16) ^ ((m&7)<<4)));
          s = MFMA16(aQ[st][kk], b, s);
        }
        #pragma unroll
        for(int r=0; r<4; r++){
          float e = __expf(s[r]);
          den[st][r] += e;
          int n = g*4 + r;
          *(short*)((char*)pw + n*256 + (((mt*16+l15)*2) ^ ((n&7)<<4))) = (short)bfbits(e);
        }
      }
      __syncthreads();
      #pragma unroll
      for(int ks=0; ks<4; ks++){
        sh8 aP = *(sh8*)((char*)pw + l15*256 + ((ks*64 + g*16) ^ ((l15&7)<<4)));
        #pragma unroll
        for(int dt=0; dt<4; dt++){
          int d = dt*16 + l15;
          sh8 bW = *(sh8*)((char*)w2L + d*256 + ((ks*64 + g*16) ^ ((d&7)<<4)));
          accO[st][dt] = MFMA16(aP, bW, accO[st][dt]);
        }
      }
      __syncthreads();
    }
  }
  #pragma unroll
  for(int st=0; st<2; st++)
    #pragma unroll
    for(int r=0; r<4; r++){
      float d_ = den[st][r];
      d_ += __shfl_xor(d_,1); d_ += __shfl_xor(d_,2);
      d_ += __shfl_xor(d_,4); d_ += __shfl_xor(d_,8);
      den[st][r] = 1.f/d_;
    }
  #pragma unroll
  for(int st=0; st<2; st++)
    #pragma unroll
    for(int dt=0; dt<4; dt++)
      #pragma unroll
      for(int r=0; r<4; r++){
        int row = n0 + wv*32 + st*16 + g*4 + r;
        F[(size_t)row*CDIM + h*DHEAD + dt*16 + l15] = accO[st][dt][r]*den[st][r];
      }
}

// ---------------- MFMA flash a3v ----------------
__global__ __launch_bounds__(256) void k_a3v_mfma(const float* __restrict__ ql,
    const float* __restrict__ Kb, const float* __restrict__ Vb,
    float* __restrict__ numP, float* __restrict__ denP){
  __shared__ short kL[128*64];
  __shared__ short vL[64*128];
  __shared__ short pL[4][16*128];
  int h = blockIdx.x, c = blockIdx.y;
  int t = threadIdx.x, lane = t & 63, wv = t >> 6, g = lane >> 4, l15 = lane & 15;
  const float* qlh = ql + (size_t)h*NLAND*DHEAD;
  sh8 aQ[4][2];
  #pragma unroll
  for(int st=0; st<4; st++)
    #pragma unroll
    for(int kk=0; kk<2; kk++){
      const float* p = qlh + (size_t)(wv*64 + st*16 + l15)*DHEAD + kk*32 + g*8;
      aQ[st][kk] = pack8f(*(const float4*)p, *(const float4*)(p+4));
    }
  f4 accO[4][4] = {};
  float den[4][4] = {};
  short* pw = pL[wv];
  for(int half=0; half<2; half++){
    const float* Kh = Kb + ((size_t)h*NPAD + (size_t)c*256 + half*128)*DHEAD;
    const float* Vh = Vb + ((size_t)h*NPAD + (size_t)c*256 + half*128)*DHEAD;
    __syncthreads();
    #pragma unroll
    for(int it=0; it<4; it++){
      int gi = t + it*256;
      int m = gi >> 3, db = (gi & 7) * 8;
      const float* p = Kh + (size_t)m*DHEAD + db;
      *(sh8*)((char*)kL + m*128 + ((db*2) ^ ((m&7)<<4))) =
          pack8f(*(const float4*)p, *(const float4*)(p+4));
    }
    #pragma unroll
    for(int it=0; it<8; it++){
      int idx = t + it*256;
      int m = idx & 127, d0 = (idx >> 7) * 4;
      float4 v = *(const float4*)(Vh + (size_t)m*DHEAD + d0);
      float vv[4] = {v.x, v.y, v.z, v.w};
      #pragma unroll
      for(int i=0;i<4;i++){
        int d = d0 + i;
        *(short*)((char*)vL + d*256 + ((m*2) ^ ((d&7)<<4))) = (short)bfbits(vv[i]);
      }
    }
    __syncthreads();
    #pragma unroll
    for(int st=0; st<4; st++){
      #pragma unroll
      for(int mt=0; mt<8; mt++){
        f4 s = {};
        #pragma unroll
        for(int kk=0; kk<2; kk++){
          int m = mt*16 + l15;
          sh8 b = *(sh8*)((char*)kL + m*128 + ((kk*64 + g*16) ^ ((m&7)<<4)));
          s = MFMA16(aQ[st][kk], b, s);
        }
        #pragma unroll
        for(int r=0; r<4; r++){
          float e = __expf(s[r]);
          den[st][r] += e;
          int n = g*4 + r;
          *(short*)((char*)pw + n*256 + (((mt*16+l15)*2) ^ ((n&7)<<4))) = (short)bfbits(e);
        }
      }
      __syncthreads();
      #pragma unroll
      for(int ks=0; ks<4; ks++){
        sh8 aP = *(sh8*)((char*)pw + l15*256 + ((ks*64 + g*16) ^ ((l15&7)<<4)));
        #pragma unroll
        for(int dt=0; dt<4; dt++){
          int d = dt*16 + l15;
          sh8 bV = *(sh8*)((char*)vL + d*256 + ((ks*64 + g*16) ^ ((d&7)<<4)));
          accO[st][dt] = MFMA16(aP, bV, accO[st][dt]);
        }
      }
      __syncthreads();
    }
  }
  #pragma unroll
  for(int st=0; st<4; st++)
    #pragma unroll
    for(int r=0; r<4; r++){
      float d_ = den[st][r];
      d_ += __shfl_xor(d_,1); d_ += __shfl_xor(d_,2);
      d_ += __shfl_xor(d_,4); d_ += __shfl_xor(d_,8);
      den[st][r] = d_;
    }
  size_t base = ((size_t)h*NCHUNK + c)*NLAND;
  #pragma unroll
  for(int st=0; st<4; st++){
    #pragma unroll
    for(int r=0; r<4; r++){
      int row = wv*64 + st*16 + g*4 + r;
      if(l15 == 0) denP[base + row] = den[st][r];
      #pragma unroll
      for(int dt=0; dt<4; dt++)
        numP[(base + row)*DHEAD + dt*16 + l15] = accO[st][dt][r];
    }
  }
}

__global__ void k_a3v_comb(const float* __restrict__ numP, const float* __restrict__ denP,
                           float* __restrict__ a3v){
  int bidx = blockIdx.x;           // h*256 + m
  int h = bidx >> 8, m = bidx & 255;
  int d = threadIdx.x;
  float s = 0.f, den = 0.f;
  for(int c=0;c<NCHUNK;c++){
    s += numP[(((size_t)h*NCHUNK + c)*NLAND + m)*DHEAD + d];
    den += denP[((size_t)h*NCHUNK + c)*NLAND + m];
  }
  a3v[((size_t)h*NLAND + m)*DHEAD + d] = s / den;
}

// ---------------- residual depthwise conv (k=33), FIR-tiled ----------------
// grid (NPAD/128, NHEAD); V tile staged once, 32 reg accumulators/thread
__global__ __launch_bounds__(256) void k_resconv(const float* __restrict__ Vb,
    const float* __restrict__ rw, float* __restrict__ F){
  __shared__ float vs[160][64];
  int n0 = blockIdx.x*128, h = blockIdx.y;
  int t = threadIdx.x;
  const float* vh = Vb + (size_t)h*NPAD*DHEAD;
  #pragma unroll
  for(int i=0;i<10;i++){
    int idx = t + i*256;
    int r = idx >> 4, dq = (idx & 15)*4;
    int n = n0 - 16 + r;
    float4 v = (n>=0 && n<NPAD) ? *(const float4*)(vh + (size_t)n*DHEAD + dq)
                                : make_float4(0.f,0.f,0.f,0.f);
    *(float4*)&vs[r][dq] = v;
  }
  float w[33];
  #pragma unroll
  for(int j=0;j<33;j++) w[j] = rw[h*33+j];
  __syncthreads();
  int d = t & 63, half = t >> 6;
  float acc[32];
  #pragma unroll
  for(int r=0;r<32;r++) acc[r] = 0.f;
  #pragma unroll
  for(int p=0;p<64;p++){
    float vv = vs[half*32 + p][d];
    #pragma unroll
    for(int j=0;j<33;j++){
      int r = p - j;
      if(r >= 0 && r < 32) acc[r] += w[j]*vv;
    }
  }
  #pragma unroll
  for(int r=0;r<32;r++){
    int n = n0 + half*32 + r;
    F[(size_t)n*CDIM + h*DHEAD + d] += acc[r];
  }
}

// ---------------- transpose (weights only) ----------------
__global__ void k_transpose(const float* __restrict__ in, float* __restrict__ out,
                            int R, int C){
  __shared__ float tile[32][33];
  int r0 = blockIdx.x*32, c0 = blockIdx.y*32;
  int tx = threadIdx.x, ty = threadIdx.y;
  #pragma unroll
  for(int r=0;r<4;r++) tile[ty + r*8][tx] = in[(size_t)(r0 + ty + r*8)*C + c0 + tx];
  __syncthreads();
  #pragma unroll
  for(int r=0;r<4;r++) out[(size_t)(c0 + ty + r*8)*R + r0 + tx] = tile[tx][ty + r*8];
}

// ---------------- PPEG direct on row-major [n][c] ----------------
// grid (64 spatial tiles, 32 ch-groups of 16); FIR over columns, weights in regs
__global__ __launch_bounds__(256) void k_ppeg2(const float* __restrict__ X,
    const float* __restrict__ w7, const float* __restrict__ b7,
    const float* __restrict__ w5, const float* __restrict__ b5,
    const float* __restrict__ w3, const float* __restrict__ b3,
    float* __restrict__ Y){
  __shared__ float patch[484][20];
  int cg = blockIdx.y;
  int ti = blockIdx.x >> 3, tj = blockIdx.x & 7;
  int t = threadIdx.x;
  int i0 = ti*16 - 3, j0 = tj*16 - 3;
  for(int idx = t; idx < 1936; idx += 256){
    int p = idx >> 2, cq = (idx & 3) * 4;
    int gi = i0 + p/22, gj = j0 + p%22;
    float4 v = make_float4(0.f,0.f,0.f,0.f);
    if(gi>=0 && gi<128 && gj>=0 && gj<128)
      v = *(const float4*)(X + (size_t)(gi*128+gj)*CDIM + cg*16 + cq);
    *(float4*)&patch[p][cq] = v;
  }
  int c = t & 15, sg = t >> 4;     // output row i = sg, 16 cols each
  int cglob = cg*16 + c;
  float wr[83];
  #pragma unroll
  for(int k=0;k<49;k++) wr[k] = w7[cglob*49+k];
  #pragma unroll
  for(int k=0;k<25;k++) wr[49+k] = w5[cglob*25+k];
  #pragma unroll
  for(int k=0;k<9;k++)  wr[74+k] = w3[cglob*9+k];
  float bsum = b7[cglob] + b5[cglob] + b3[cglob];
  __syncthreads();
  float acc[16];
  #pragma unroll
  for(int j=0;j<16;j++) acc[j] = patch[(sg+3)*22 + (j+3)][c] + bsum;
  #pragma unroll
  for(int a=0;a<7;a++)
    #pragma unroll
    for(int x=0;x<22;x++){
      float vv = patch[(sg+a)*22 + x][c];
      #pragma unroll
      for(int bq=0;bq<7;bq++){
        int j = x - bq;
        if(j>=0 && j<16) acc[j] += wr[a*7+bq]*vv;
      }
    }
  #pragma unroll
  for(int a=0;a<5;a++)
    #pragma unroll
    for(int x=1;x<21;x++){
      float vv = patch[(sg+a+1)*22 + x][c];
      #pragma unroll
      for(int bq=0;bq<5;bq++){
        int j = x - 1 - bq;
        if(j>=0 && j<16) acc[j] += wr[49+a*5+bq]*vv;
      }
    }
  #pragma unroll
  for(int a=0;a<3;a++)
    #pragma unroll
    for(int x=2;x<20;x++){
      float vv = patch[(sg+a+2)*22 + x][c];
      #pragma unroll
      for(int bq=0;bq<3;bq++){
        int j = x - 2 - bq;
        if(j>=0 && j<16) acc[j] += wr[74+a*3+bq]*vv;
      }
    }
  #pragma unroll
  for(int j=0;j<16;j++)
    Y[(size_t)((ti*16+sg)*128 + tj*16+j)*CDIM + cglob] = acc[j];
}

// ---------------- final LN(row0) + fc2 ----------------
__global__ __launch_bounds__(512) void k_final(const float* __restrict__ A,
    const float* __restrict__ g, const float* __restrict__ b,
    const float* __restrict__ w, const float* __restrict__ bias,
    float* __restrict__ outp){
  __shared__ float red[8];
  int t = threadIdx.x, wv = t >> 6;
  float x = A[t];
  float s = wave_sum(x);
  if((t & 63) == 0) red[wv] = s;
  __syncthreads();
  float mu = 0;
  #pragma unroll
  for(int i=0;i<8;i++) mu += red[i];
  mu *= (1.f/512.f);
  __syncthreads();
  float dx = x - mu;
  s = wave_sum(dx*dx);
  if((t & 63) == 0) red[wv] = s;
  __syncthreads();
  float var = 0;
  #pragma unroll
  for(int i=0;i<8;i++) var += red[i];
  var *= (1.f/512.f);
  float xn = dx * rsqrtf(var + 1e-5f) * g[t] + b[t];
  __syncthreads();
  for(int o=0;o<4;o++){
    s = wave_sum(xn * w[t*4 + o]);
    if((t & 63) == 0) red[wv] = s;
    __syncthreads();
    if(t == 0){
      float r = 0;
      #pragma unroll
      for(int i=0;i<8;i++) r += red[i];
      outp[o] = r + bias[o];
    }
    __syncthreads();
  }
}

extern "C" void kernel_launch(void* const* d_in, const int* in_sizes, int n_in,
                              void* d_out, int out_size, void* d_ws, size_t ws_size,
                              hipStream_t stream) {
  (void)in_sizes; (void)n_in; (void)out_size; (void)ws_size;
  const float* data_x = (const float*)d_in[0];
  const float* fc1_w  = (const float*)d_in[1];
  const float* fc1_b  = (const float*)d_in[2];
  const float* cls_tk = (const float*)d_in[3];
  const float* ng[2]  = {(const float*)d_in[4],  (const float*)d_in[16]};
  const float* nb[2]  = {(const float*)d_in[5],  (const float*)d_in[17]};
  const float* qkvw[2]= {(const float*)d_in[6],  (const float*)d_in[18]};
  const float* outw[2]= {(const float*)d_in[7],  (const float*)d_in[19]};
  const float* outb[2]= {(const float*)d_in[8],  (const float*)d_in[20]};
  const float* resw[2]= {(const float*)d_in[9],  (const float*)d_in[21]};
  const float* w7 = (const float*)d_in[10]; const float* pb7 = (const float*)d_in[11];
  const float* w5 = (const float*)d_in[12]; const float* pb5 = (const float*)d_in[13];
  const float* w3 = (const float*)d_in[14]; const float* pb3 = (const float*)d_in[15];
  const float* norm_g = (const float*)d_in[22];
  const float* norm_b = (const float*)d_in[23];
  const float* fc2_w  = (const float*)d_in[24];
  const float* fc2_b  = (const float*)d_in[25];

  float* ws = (float*)d_ws;
  float* Ab   = ws;                         // 16385*512 (layer-0 h base)
  float* Bb   = Ab + (size_t)TOK*CDIM;      // 16640*512 (L0 ln-out; then post-ppeg h base)
  float* Qb   = Bb + (size_t)NPAD*CDIM;
  float* Kb   = Qb + (size_t)NPAD*CDIM;
  float* Vb   = Kb + (size_t)NPAD*CDIM;
  float* Fb   = Vb + (size_t)NPAD*CDIM;     // L1 ln-out; a3v numP scratch; pre-proj F
  float* qlb  = Fb + (size_t)NPAD*CDIM;     // 8*256*64
  float* klb  = qlb + NHEAD*NLAND*DHEAD;
  float* a2b  = klb + NHEAD*NLAND*DHEAD;    // 8*256*256
  float* z0b  = a2b + NHEAD*NLAND*NLAND;
  float* z1b  = z0b + NHEAD*NLAND*NLAND;
  float* Xb_  = z1b + NHEAD*NLAND*NLAND;
  float* Tb_  = Xb_ + NHEAD*NLAND*NLAND;
  float* Ub_  = Tb_ + NHEAD*NLAND*NLAND;
  float* a3vb = Ub_ + NHEAD*NLAND*NLAND;    // 8*256*64
  float* w2tb = a3vb + NHEAD*NLAND*DHEAD;   // 8*64*256 (transposed w2)
  float* denP = w2tb + NHEAD*DHEAD*NLAND;   // 8*65*256
  float* hmax = denP + NHEAD*NCHUNK*NLAND;  // 8
  float* scal = hmax + 8;                   // 1
  unsigned* bar = (unsigned*)(scal + 1);    // 2 barrier counters
  float* fc1T = scal + 8;                   // 512*1024
  float* qkvT0= fc1T + 512*1024;            // 1536*512
  float* qkvT1= qkvT0 + 1536*512;
  float* outT0= qkvT1 + 1536*512;           // 512*512
  float* outT1= outT0 + 512*512;
  float* qkvT[2] = {qkvT0, qkvT1};
  float* outT[2] = {outT0, outT1};

  hipMemsetAsync((void*)bar, 0, 2*sizeof(unsigned), stream);

  // weight transposes (WT[n][k])
  k_transpose<<<dim3(32,16), dim3(32,8), 0, stream>>>(fc1_w, fc1T, 1024, 512);
  k_transpose<<<dim3(16,48), dim3(32,8), 0, stream>>>(qkvw[0], qkvT0, 512, 1536);
  k_transpose<<<dim3(16,48), dim3(32,8), 0, stream>>>(qkvw[1], qkvT1, 512, 1536);
  k_transpose<<<dim3(16,16), dim3(32,8), 0, stream>>>(outw[0], outT0, 512, 512);
  k_transpose<<<dim3(16,16), dim3(32,8), 0, stream>>>(outw[1], outT1, 512, 512);

  k_copyrow<<<1, 512, 0, stream>>>(Ab, cls_tk);
  k_gemm_mfma<0><<<dim3(4, 128), 256, 0, stream>>>(data_x, 1024, fc1T, 1024, fc1_b,
                                                   Ab + CDIM, nullptr, nullptr, 16384);
  float* base[2]  = {Ab, Bb};
  float* lnout[2] = {Bb, Fb};
  for(int L=0; L<2; L++){
    k_ln_pad<<<NPAD/4, 256, 0, stream>>>(base[L], ng[L], nb[L], lnout[L]);
    k_gemm_mfma<1><<<dim3(12, 130), 256, 0, stream>>>(lnout[L], CDIM, qkvT[L], CDIM, nullptr,
                                                      Qb, Kb, Vb, NPAD);
    k_landmark<<<NHEAD*NLAND, 64, 0, stream>>>(Qb, qlb);
    k_landmark<<<NHEAD*NLAND, 64, 0, stream>>>(Kb, klb);
    k_a2<<<dim3(4, NHEAD), 256, 0, stream>>>(qlb, klb, a2b);
    k_colmax<<<NHEAD, 256, 0, stream>>>(a2b, hmax);
    k_scal<<<1, 64, 0, stream>>>(hmax, scal);
    k_zinit<<<dim3(256, NHEAD), 256, 0, stream>>>(a2b, scal, z0b);
    k_pinv<<<256, 256, 0, stream>>>(a2b, z0b, z1b, Xb_, Tb_, Ub_, bar + L);
    // final z is in z0b after 6 iterations
    k_a3v_mfma<<<dim3(NHEAD, NCHUNK), 256, 0, stream>>>(qlb, Kb, Vb, Fb, denP);
    k_a3v_comb<<<NHEAD*NLAND, 64, 0, stream>>>(Fb, denP, a3vb);
    k_sgemm2<0,1><<<dim3(1,4,NHEAD), 256, 0, stream>>>(z0b, a3vb, w2tb, 256,64,256,
                                                       65536,16384,16384, 0.f, 1.f);
    k_a1_mfma<<<dim3(130, NHEAD), 256, 0, stream>>>(Qb, klb, w2tb, Fb);
    k_resconv<<<dim3(130, NHEAD), 256, 0, stream>>>(Vb, resw[L], Fb);
    k_gemm_mfma<2><<<dim3(4, 129), 256, 0, stream>>>(Fb + (size_t)PAD0*CDIM, CDIM,
                                                     outT[L], CDIM, outb[L],
                                                     base[L], nullptr, nullptr, TOK);
    if(L == 0){
      k_ppeg2<<<dim3(64, 32), 256, 0, stream>>>(Ab + CDIM, w7, pb7, w5, pb5, w3, pb3,
                                                Bb + CDIM);
      k_copyrow<<<1, 512, 0, stream>>>(Bb, Ab);
    }
  }
  k_final<<<1, 512, 0, stream>>>(Bb, norm_g, norm_b, fc2_w, fc2_b, (float*)d_out);
}

// Round 5
// 1940.099 us; speedup vs baseline: 1.3230x; 1.3230x over previous
//
#include <hip/hip_runtime.h>
#include <hip/hip_bf16.h>

#define NPAD 16640
#define TOK  16385
#define CDIM 512
#define NHEAD 8
#define DHEAD 64
#define NLAND 256
#define LFAC  65
#define PAD0  255
#define NCHUNK 65   // chunks of 256 rows: 65*256 = 16640

typedef __attribute__((ext_vector_type(8))) short sh8;
typedef __attribute__((ext_vector_type(4))) float f4;

__device__ __forceinline__ float wave_sum(float v){
  #pragma unroll
  for(int o=32;o;o>>=1) v += __shfl_xor(v,o);
  return v;
}
__device__ __forceinline__ float wave_max(float v){
  #pragma unroll
  for(int o=32;o;o>>=1) v = fmaxf(v, __shfl_xor(v,o));
  return v;
}

// bf16 RNE pack helpers
__device__ __forceinline__ unsigned bfbits(float x){
  unsigned u = __float_as_uint(x);
  return (u + 0x7fffu + ((u >> 16) & 1u)) >> 16;
}
__device__ __forceinline__ float bf2f(short s){
  return __uint_as_float(((unsigned)(unsigned short)s) << 16);
}
__device__ __forceinline__ sh8 pack8f(float4 a, float4 b){
  sh8 r;
  r[0]=(short)bfbits(a.x); r[1]=(short)bfbits(a.y); r[2]=(short)bfbits(a.z); r[3]=(short)bfbits(a.w);
  r[4]=(short)bfbits(b.x); r[5]=(short)bfbits(b.y); r[6]=(short)bfbits(b.z); r[7]=(short)bfbits(b.w);
  return r;
}
#define MFMA16(a,b,c) __builtin_amdgcn_mfma_f32_16x16x32_bf16(a,b,c,0,0,0)

// ---------------- row copy (cls token) ----------------
__global__ void k_copyrow(float* dst, const float* __restrict__ src){
  dst[threadIdx.x] = src[threadIdx.x];
}

// ---------------- layernorm + front pad ----------------
__global__ __launch_bounds__(256) void k_ln_pad(const float* __restrict__ A,
    const float* __restrict__ g, const float* __restrict__ b, float* __restrict__ B){
  int w = threadIdx.x >> 6, lane = threadIdx.x & 63;
  int row = blockIdx.x*4 + w;
  float* out = B + (size_t)row*CDIM;
  if(row < PAD0){
    #pragma unroll
    for(int i=0;i<8;i++) out[lane + i*64] = 0.f;
    return;
  }
  const float* x = A + (size_t)(row-PAD0)*CDIM;
  int c0 = lane*4, c1 = 256 + lane*4;
  float4 v0 = *(const float4*)(x + c0);
  float4 v1 = *(const float4*)(x + c1);
  float xs[8] = {v0.x,v0.y,v0.z,v0.w,v1.x,v1.y,v1.z,v1.w};
  float s = 0;
  #pragma unroll
  for(int i=0;i<8;i++) s += xs[i];
  s = wave_sum(s);
  float mu = s * (1.f/512.f);
  float vs = 0;
  #pragma unroll
  for(int i=0;i<8;i++){ float d = xs[i]-mu; vs += d*d; }
  vs = wave_sum(vs) * (1.f/512.f);
  float rs = rsqrtf(vs + 1e-5f);
  float4 g0 = *(const float4*)(g + c0); float4 g1 = *(const float4*)(g + c1);
  float4 b0 = *(const float4*)(b + c0); float4 b1 = *(const float4*)(b + c1);
  float4 o0, o1;
  o0.x = (xs[0]-mu)*rs*g0.x + b0.x; o0.y = (xs[1]-mu)*rs*g0.y + b0.y;
  o0.z = (xs[2]-mu)*rs*g0.z + b0.z; o0.w = (xs[3]-mu)*rs*g0.w + b0.w;
  o1.x = (xs[4]-mu)*rs*g1.x + b1.x; o1.y = (xs[5]-mu)*rs*g1.y + b1.y;
  o1.z = (xs[6]-mu)*rs*g1.z + b1.z; o1.w = (xs[7]-mu)*rs*g1.w + b1.w;
  *(float4*)(out + c0) = o0;
  *(float4*)(out + c1) = o1;
}

// ---------------- MFMA GEMM: C[M,N] = A[M,K] @ WT[N,K]^T, bf16 inputs ----------------
template<int MODE>
__global__ __launch_bounds__(256) void k_gemm_mfma(const float* __restrict__ A, int lda,
    const float* __restrict__ WT, int K, const float* __restrict__ bias,
    float* out0, float* out1, float* out2, int M){
  __shared__ short As[128*32];
  __shared__ short Bs[128*32];
  int t = threadIdx.x, lane = t & 63, wv = t >> 6, g = lane >> 4, l15 = lane & 15;
  int row0 = blockIdx.y*128, n0 = blockIdx.x*128;
  int wm = (wv>>1)*64, wn = (wv&1)*64;
  f4 acc[4][4] = {};
  for(int k0 = 0; k0 < K; k0 += 32){
    #pragma unroll
    for(int u=0; u<2; u++){
      int gi = t + u*256;               // 512 granules of 8 elems
      int m = gi >> 2, kb = (gi & 3) * 8;
      float4 va = make_float4(0,0,0,0), vb = make_float4(0,0,0,0);
      int gr = row0 + m;
      if(gr < M){
        va = *(const float4*)(A + (size_t)gr*lda + k0 + kb);
        vb = *(const float4*)(A + (size_t)gr*lda + k0 + kb + 4);
      }
      int swz = (((m&3) ^ ((m>>2)&3)) << 4);
      *(sh8*)((char*)As + m*64 + ((kb*2) ^ swz)) = pack8f(va, vb);
      float4 wa = *(const float4*)(WT + (size_t)(n0+m)*K + k0 + kb);
      float4 wb = *(const float4*)(WT + (size_t)(n0+m)*K + k0 + kb + 4);
      *(sh8*)((char*)Bs + m*64 + ((kb*2) ^ swz)) = pack8f(wa, wb);
    }
    __syncthreads();
    sh8 af[4], bf[4];
    #pragma unroll
    for(int mt=0; mt<4; mt++){
      int r = wm + mt*16 + l15;
      af[mt] = *(sh8*)((char*)As + r*64 + ((g*16) ^ (((r&3)^((r>>2)&3))<<4)));
    }
    #pragma unroll
    for(int nt=0; nt<4; nt++){
      int r = wn + nt*16 + l15;
      bf[nt] = *(sh8*)((char*)Bs + r*64 + ((g*16) ^ (((r&3)^((r>>2)&3))<<4)));
    }
    #pragma unroll
    for(int mt=0; mt<4; mt++)
      #pragma unroll
      for(int nt=0; nt<4; nt++)
        acc[mt][nt] = MFMA16(af[mt], bf[nt], acc[mt][nt]);
    __syncthreads();
  }
  #pragma unroll
  for(int mt=0; mt<4; mt++){
    #pragma unroll
    for(int r=0; r<4; r++){
      int gm = row0 + wm + mt*16 + g*4 + r;
      if(gm >= M) continue;
      #pragma unroll
      for(int nt=0; nt<4; nt++){
        int gn = n0 + wn + nt*16 + l15;
        float v = acc[mt][nt][r];
        if(MODE == 0){
          v += bias[gn];
          out0[(size_t)gm*CDIM + gn] = v > 0.f ? v : 0.f;
        } else if(MODE == 1){
          int p = gn >> 9, rr = gn & 511;
          int hh = rr >> 6, dd = rr & 63;
          if(p == 0) v *= 0.125f;
          float* dst = (p==0) ? out0 : (p==1 ? out1 : out2);
          dst[((size_t)hh*NPAD + gm)*DHEAD + dd] = v;
        } else {
          out0[(size_t)gm*CDIM + gn] += v + bias[gn];
        }
      }
    }
  }
}

// ---------------- landmark means ----------------
__global__ void k_landmark(const float* __restrict__ src, float* __restrict__ dst){
  int bidx = blockIdx.x;               // h*256 + m
  int h = bidx >> 8, m = bidx & 255, d = threadIdx.x;
  const float* p = src + ((size_t)h*NPAD + (size_t)m*LFAC)*DHEAD + d;
  float s = 0;
  for(int j=0;j<LFAC;j++) s += p[(size_t)j*DHEAD];
  dst[(size_t)bidx*DHEAD + d] = s * (1.f/LFAC);
}

// ---------------- a2 = softmax(ql @ kl^T), f32 + bf16 copies ----------------
__global__ __launch_bounds__(256) void k_a2(const float* __restrict__ ql,
    const float* __restrict__ kl, float* __restrict__ a2, short* __restrict__ a2bf){
  __shared__ __hip_bfloat16 klt[64*256];  // [d][m]
  int h = blockIdx.y;
  int t = threadIdx.x;
  const float* klh = kl + (size_t)h*NLAND*DHEAD;
  for(int r=0;r<64;r++){
    int idx = r*256 + t;
    int d = idx >> 8, m = idx & 255;
    klt[idx] = __float2bfloat16(klh[m*DHEAD + d]);
  }
  __syncthreads();
  int w = t >> 6, lane = t & 63;
  const float* qlh = ql + (size_t)h*NLAND*DHEAD;
  for(int rr=0; rr<16; rr++){
    int m = blockIdx.x*64 + w*16 + rr;
    const float* q = qlh + (size_t)m*DHEAD;
    float s[4] = {0,0,0,0};
    #pragma unroll
    for(int d=0; d<64; d++){
      float qv = q[d];
      #pragma unroll
      for(int qd=0; qd<4; qd++)
        s[qd] += qv * __bfloat162float(klt[d*256 + qd*64 + lane]);
    }
    float e[4], den = 0.f;
    #pragma unroll
    for(int qd=0; qd<4; qd++){ e[qd] = __expf(s[qd]); den += e[qd]; }
    den = wave_sum(den);
    float inv = 1.f/den;
    size_t rowo = ((size_t)h*NLAND + m)*NLAND;
    #pragma unroll
    for(int qd=0; qd<4; qd++){
      float v = e[qd]*inv;
      a2[rowo + qd*64 + lane] = v;
      a2bf[rowo + qd*64 + lane] = (short)bfbits(v);
    }
  }
}

// ---------------- pinv init ----------------
__global__ void k_colmax(const float* __restrict__ a2, float* __restrict__ hmax){
  __shared__ float red[4];
  int h = blockIdx.x, t = threadIdx.x;
  const float* p = a2 + (size_t)h*65536 + t;
  float s = 0;
  for(int m=0;m<256;m++) s += p[(size_t)m*256];
  float mx = wave_max(s);
  if((t & 63) == 0) red[t>>6] = mx;
  __syncthreads();
  if(t == 0) hmax[h] = fmaxf(fmaxf(red[0],red[1]), fmaxf(red[2],red[3]));
}
__global__ void k_scal(const float* __restrict__ hmax, float* __restrict__ scal){
  int t = threadIdx.x;
  float v = (t < 8) ? hmax[t] : -1e30f;
  v = wave_max(v);
  if(t == 0) scal[0] = v;
}
// z0 (bf16, both forms) = a2^T / s
__global__ void k_zinit2(const float* __restrict__ a2, const float* __restrict__ scal,
                         short* __restrict__ zrm, short* __restrict__ ztr){
  int h = blockIdx.y;
  int idx = blockIdx.x*256 + threadIdx.x;   // 0..65535
  int m = idx >> 8, j = idx & 255;
  float inv = 1.f / scal[0];
  size_t off = (size_t)h*65536;
  zrm[off + idx] = (short)bfbits(a2[off + (size_t)j*256 + m] * inv);
  ztr[off + idx] = (short)bfbits(a2[off + idx] * inv);
}

// ---------------- fused per-head MFMA pinv ----------------
// One block per head, 512 threads (8 waves), all syncs intra-block.
// Stage computes C = A @ B via TN-form: A row-major bf16, B-operand staged
// in LDS as Q[n][k] = (ALPHA? alpha*I - Btr : Btr), n in 2 halves of 128.
// Outputs: WRT bit0 -> Ctr (transposed, contiguous 8B stores),
//          bit1 -> Crm (row-major bf16), bit2 -> Cf32 (row-major f32).
template<int WRT, bool ALPHA>
__device__ __forceinline__ void pinv_stage(const short* __restrict__ Arow,
    const short* __restrict__ Btr, float alpha, float beta,
    short* __restrict__ Ctr, short* __restrict__ Crm, float* __restrict__ Cf32,
    short* Bq, int wv, int g, int l15, int t){
  for(int nh=0; nh<2; nh++){
    __syncthreads();   // previous users of Bq done
    #pragma unroll
    for(int i=0;i<8;i++){
      int gi = t + i*512;              // 4096 granules of 8
      int n = gi >> 5, kb = (gi & 31) * 8;
      sh8 v = *(const sh8*)(Btr + (size_t)(nh*128 + n)*256 + kb);
      if(ALPHA){
        int ng = nh*128 + n;
        #pragma unroll
        for(int e=0;e<8;e++){
          float f = ((ng == kb+e) ? alpha : 0.f) - bf2f(v[e]);
          v[e] = (short)bfbits(f);
        }
      }
      *(sh8*)((char*)Bq + n*512 + ((kb*2) ^ ((n&7)<<4))) = v;
    }
    __syncthreads();
    f4 acc[2][8] = {};
    for(int ks=0; ks<8; ks++){
      sh8 a0 = *(const sh8*)(Arow + (size_t)(wv*32 + l15)*256 + ks*32 + g*8);
      sh8 a1 = *(const sh8*)(Arow + (size_t)(wv*32 + 16 + l15)*256 + ks*32 + g*8);
      #pragma unroll
      for(int nt=0; nt<8; nt++){
        int n = nt*16 + l15;
        sh8 b = *(sh8*)((char*)Bq + n*512 + ((ks*64 + g*16) ^ ((n&7)<<4)));
        acc[0][nt] = MFMA16(a0, b, acc[0][nt]);
        acc[1][nt] = MFMA16(a1, b, acc[1][nt]);
      }
    }
    #pragma unroll
    for(int mt=0; mt<2; mt++){
      int m0 = wv*32 + mt*16 + g*4;
      #pragma unroll
      for(int nt=0; nt<8; nt++){
        int n = nh*128 + nt*16 + l15;
        f4 v = acc[mt][nt];
        v[0]*=beta; v[1]*=beta; v[2]*=beta; v[3]*=beta;
        if(WRT & 1){
          short4 pk;
          pk.x=(short)bfbits(v[0]); pk.y=(short)bfbits(v[1]);
          pk.z=(short)bfbits(v[2]); pk.w=(short)bfbits(v[3]);
          *(short4*)(Ctr + (size_t)n*256 + m0) = pk;
        }
        if(WRT & 2){
          #pragma unroll
          for(int r=0;r<4;r++) Crm[(size_t)(m0+r)*256 + n] = (short)bfbits(v[r]);
        }
        if(WRT & 4){
          #pragma unroll
          for(int r=0;r<4;r++) Cf32[(size_t)(m0+r)*256 + n] = v[r];
        }
      }
    }
  }
}

__global__ __launch_bounds__(512) void k_pinv2(const short* __restrict__ a2bf,
    short* __restrict__ Xrm, short* __restrict__ Xtr,
    short* __restrict__ Ttr, short* __restrict__ Utr,
    short* __restrict__ zrm0, short* __restrict__ ztr0,
    short* __restrict__ zrm1, short* __restrict__ ztr1,
    float* __restrict__ zf32){
  __shared__ short Bq[128*256];  // 64KB
  int h = blockIdx.x;
  size_t off = (size_t)h*65536;
  const short* a2h = a2bf + off;
  short* Xr = Xrm + off; short* Xt = Xtr + off;
  short* Tt = Ttr + off; short* Ut = Utr + off;
  short* zr[2] = {zrm0 + off, zrm1 + off};
  short* zt[2] = {ztr0 + off, ztr1 + off};
  float* zf = zf32 + off;
  int t = threadIdx.x, lane = t & 63, wv = t >> 6, g = lane >> 4, l15 = lane & 15;
  int cur = 0;
  for(int it=0; it<6; it++){
    // X = a2 @ z
    pinv_stage<3,false>(a2h, zt[cur], 0.f, 1.f, Xt, Xr, nullptr, Bq, wv, g, l15, t);
    // T = X @ (7I - X)
    pinv_stage<1,true >(Xr, Xt, 7.f, 1.f, Tt, nullptr, nullptr, Bq, wv, g, l15, t);
    // U = X @ (15I - T)
    pinv_stage<1,true >(Xr, Tt, 15.f, 1.f, Ut, nullptr, nullptr, Bq, wv, g, l15, t);
    // zn = 0.25 * z @ (13I - U)
    if(it < 5)
      pinv_stage<3,true>(zr[cur], Ut, 13.f, 0.25f, zt[cur^1], zr[cur^1], nullptr,
                         Bq, wv, g, l15, t);
    else
      pinv_stage<7,true>(zr[cur], Ut, 13.f, 0.25f, zt[cur^1], zr[cur^1], zf,
                         Bq, wv, g, l15, t);
    cur ^= 1;
  }
}

// ---------------- batched f32 GEMM 64x64 tile (used for w2^T) ----------------
template<int TRANS, int OUTT>
__global__ __launch_bounds__(256) void k_sgemm2(const float* __restrict__ A,
    const float* __restrict__ B, float* __restrict__ C,
    int M, int N, int K, long sA, long sB, long sC, float alpha, float beta){
  __shared__ float As[32][68];
  __shared__ float Bs[32][68];
  int bh = blockIdx.z;
  const float* Ah = A + (size_t)bh*sA;
  const float* Bh = B + (size_t)bh*sB;
  float* Ch = C + (size_t)bh*sC;
  int m0 = blockIdx.y*64, n0 = blockIdx.x*64;
  int t = threadIdx.x, tx = t & 15, ty = t >> 4;
  float acc[4][4] = {};
  for(int k0=0; k0<K; k0+=32){
    #pragma unroll
    for(int u=0; u<2; u++){
      int idx = t + u*256;
      int r = idx >> 3, cb = (idx & 7) * 4;
      float4 va = *(const float4*)(Ah + (size_t)(m0+r)*K + k0 + cb);
      As[cb+0][r]=va.x; As[cb+1][r]=va.y; As[cb+2][r]=va.z; As[cb+3][r]=va.w;
      int kr = idx >> 4, nb = (idx & 15) * 4;
      float4 w = *(const float4*)(Bh + (size_t)(k0+kr)*N + n0 + nb);
      if(TRANS){
        int gk = k0 + kr;
        w.x = ((gk==n0+nb+0)?alpha:0.f) - w.x;
        w.y = ((gk==n0+nb+1)?alpha:0.f) - w.y;
        w.z = ((gk==n0+nb+2)?alpha:0.f) - w.z;
        w.w = ((gk==n0+nb+3)?alpha:0.f) - w.w;
      }
      *(float4*)&Bs[kr][nb] = w;
    }
    __syncthreads();
    #pragma unroll
    for(int k=0;k<32;k++){
      float a[4], b[4];
      *(float4*)a = *(const float4*)&As[k][ty*4];
      *(float4*)b = *(const float4*)&Bs[k][tx*4];
      #pragma unroll
      for(int i=0;i<4;i++)
        #pragma unroll
        for(int j=0;j<4;j++) acc[i][j] += a[i]*b[j];
    }
    __syncthreads();
  }
  #pragma unroll
  for(int i=0;i<4;i++){
    #pragma unroll
    for(int j=0;j<4;j++){
      int gm = m0 + ty*4 + i, gn = n0 + tx*4 + j;
      float v = acc[i][j] * beta;
      if(OUTT) Ch[(size_t)gn*M + gm] = v;
      else     Ch[(size_t)gm*N + gn] = v;
    }
  }
}

// ---------------- MFMA flash a1 ----------------
__global__ __launch_bounds__(256) void k_a1_mfma(const float* __restrict__ Qb,
    const float* __restrict__ kl, const float* __restrict__ w2t, float* __restrict__ F){
  __shared__ short klL[128*64];
  __shared__ short w2L[64*128];
  __shared__ short pL[4][16*128];
  int h = blockIdx.y, n0 = blockIdx.x*128;
  int t = threadIdx.x, lane = t & 63, wv = t >> 6, g = lane >> 4, l15 = lane & 15;
  const float* klh = kl + (size_t)h*NLAND*DHEAD;
  const float* w2h = w2t + (size_t)h*DHEAD*NLAND;
  const float* qbase = Qb + (size_t)h*NPAD*DHEAD;
  sh8 aQ[2][2];
  #pragma unroll
  for(int st=0; st<2; st++)
    #pragma unroll
    for(int kk=0; kk<2; kk++){
      const float* p = qbase + (size_t)(n0 + wv*32 + st*16 + l15)*DHEAD + kk*32 + g*8;
      aQ[st][kk] = pack8f(*(const float4*)p, *(const float4*)(p+4));
    }
  f4 accO[2][4] = {};
  float den[2][4] = {};
  short* pw = pL[wv];
  for(int half=0; half<2; half++){
    __syncthreads();
    #pragma unroll
    for(int it=0; it<4; it++){
      int gi = t + it*256;
      int m = gi >> 3, db = (gi & 7) * 8;
      const float* p = klh + (size_t)(half*128 + m)*DHEAD + db;
      *(sh8*)((char*)klL + m*128 + ((db*2) ^ ((m&7)<<4))) =
          pack8f(*(const float4*)p, *(const float4*)(p+4));
      int d = gi >> 4, mb = (gi & 15) * 8;
      const float* p2 = w2h + (size_t)d*NLAND + half*128 + mb;
      *(sh8*)((char*)w2L + d*256 + ((mb*2) ^ ((d&7)<<4))) =
          pack8f(*(const float4*)p2, *(const float4*)(p2+4));
    }
    __syncthreads();
    #pragma unroll
    for(int st=0; st<2; st++){
      #pragma unroll
      for(int mt=0; mt<8; mt++){
        f4 s = {};
        #pragma unroll
        for(int kk=0; kk<2; kk++){
          int m = mt*16 + l15;
          sh8 b = *(sh8*)((char*)klL + m*128 + ((kk*64 + g*16) ^ ((m&7)<<4)));
          s = MFMA16(aQ[st][kk], b, s);
        }
        #pragma unroll
        for(int r=0; r<4; r++){
          float e = __expf(s[r]);
          den[st][r] += e;
          int n = g*4 + r;
          *(short*)((char*)pw + n*256 + (((mt*16+l15)*2) ^ ((n&7)<<4))) = (short)bfbits(e);
        }
      }
      __syncthreads();
      #pragma unroll
      for(int ks=0; ks<4; ks++){
        sh8 aP = *(sh8*)((char*)pw + l15*256 + ((ks*64 + g*16) ^ ((l15&7)<<4)));
        #pragma unroll
        for(int dt=0; dt<4; dt++){
          int d = dt*16 + l15;
          sh8 bW = *(sh8*)((char*)w2L + d*256 + ((ks*64 + g*16) ^ ((d&7)<<4)));
          accO[st][dt] = MFMA16(aP, bW, accO[st][dt]);
        }
      }
      __syncthreads();
    }
  }
  #pragma unroll
  for(int st=0; st<2; st++)
    #pragma unroll
    for(int r=0; r<4; r++){
      float d_ = den[st][r];
      d_ += __shfl_xor(d_,1); d_ += __shfl_xor(d_,2);
      d_ += __shfl_xor(d_,4); d_ += __shfl_xor(d_,8);
      den[st][r] = 1.f/d_;
    }
  #pragma unroll
  for(int st=0; st<2; st++)
    #pragma unroll
    for(int dt=0; dt<4; dt++)
      #pragma unroll
      for(int r=0; r<4; r++){
        int row = n0 + wv*32 + st*16 + g*4 + r;
        F[(size_t)row*CDIM + h*DHEAD + dt*16 + l15] = accO[st][dt][r]*den[st][r];
      }
}

// ---------------- MFMA flash a3v ----------------
__global__ __launch_bounds__(256) void k_a3v_mfma(const float* __restrict__ ql,
    const float* __restrict__ Kb, const float* __restrict__ Vb,
    float* __restrict__ numP, float* __restrict__ denP){
  __shared__ short kL[128*64];
  __shared__ short vL[64*128];
  __shared__ short pL[4][16*128];
  int h = blockIdx.x, c = blockIdx.y;
  int t = threadIdx.x, lane = t & 63, wv = t >> 6, g = lane >> 4, l15 = lane & 15;
  const float* qlh = ql + (size_t)h*NLAND*DHEAD;
  sh8 aQ[4][2];
  #pragma unroll
  for(int st=0; st<4; st++)
    #pragma unroll
    for(int kk=0; kk<2; kk++){
      const float* p = qlh + (size_t)(wv*64 + st*16 + l15)*DHEAD + kk*32 + g*8;
      aQ[st][kk] = pack8f(*(const float4*)p, *(const float4*)(p+4));
    }
  f4 accO[4][4] = {};
  float den[4][4] = {};
  short* pw = pL[wv];
  for(int half=0; half<2; half++){
    const float* Kh = Kb + ((size_t)h*NPAD + (size_t)c*256 + half*128)*DHEAD;
    const float* Vh = Vb + ((size_t)h*NPAD + (size_t)c*256 + half*128)*DHEAD;
    __syncthreads();
    #pragma unroll
    for(int it=0; it<4; it++){
      int gi = t + it*256;
      int m = gi >> 3, db = (gi & 7) * 8;
      const float* p = Kh + (size_t)m*DHEAD + db;
      *(sh8*)((char*)kL + m*128 + ((db*2) ^ ((m&7)<<4))) =
          pack8f(*(const float4*)p, *(const float4*)(p+4));
    }
    #pragma unroll
    for(int it=0; it<8; it++){
      int idx = t + it*256;
      int m = idx & 127, d0 = (idx >> 7) * 4;
      float4 v = *(const float4*)(Vh + (size_t)m*DHEAD + d0);
      float vv[4] = {v.x, v.y, v.z, v.w};
      #pragma unroll
      for(int i=0;i<4;i++){
        int d = d0 + i;
        *(short*)((char*)vL + d*256 + ((m*2) ^ ((d&7)<<4))) = (short)bfbits(vv[i]);
      }
    }
    __syncthreads();
    #pragma unroll
    for(int st=0; st<4; st++){
      #pragma unroll
      for(int mt=0; mt<8; mt++){
        f4 s = {};
        #pragma unroll
        for(int kk=0; kk<2; kk++){
          int m = mt*16 + l15;
          sh8 b = *(sh8*)((char*)kL + m*128 + ((kk*64 + g*16) ^ ((m&7)<<4)));
          s = MFMA16(aQ[st][kk], b, s);
        }
        #pragma unroll
        for(int r=0; r<4; r++){
          float e = __expf(s[r]);
          den[st][r] += e;
          int n = g*4 + r;
          *(short*)((char*)pw + n*256 + (((mt*16+l15)*2) ^ ((n&7)<<4))) = (short)bfbits(e);
        }
      }
      __syncthreads();
      #pragma unroll
      for(int ks=0; ks<4; ks++){
        sh8 aP = *(sh8*)((char*)pw + l15*256 + ((ks*64 + g*16) ^ ((l15&7)<<4)));
        #pragma unroll
        for(int dt=0; dt<4; dt++){
          int d = dt*16 + l15;
          sh8 bV = *(sh8*)((char*)vL + d*256 + ((ks*64 + g*16) ^ ((d&7)<<4)));
          accO[st][dt] = MFMA16(aP, bV, accO[st][dt]);
        }
      }
      __syncthreads();
    }
  }
  #pragma unroll
  for(int st=0; st<4; st++)
    #pragma unroll
    for(int r=0; r<4; r++){
      float d_ = den[st][r];
      d_ += __shfl_xor(d_,1); d_ += __shfl_xor(d_,2);
      d_ += __shfl_xor(d_,4); d_ += __shfl_xor(d_,8);
      den[st][r] = d_;
    }
  size_t base = ((size_t)h*NCHUNK + c)*NLAND;
  #pragma unroll
  for(int st=0; st<4; st++){
    #pragma unroll
    for(int r=0; r<4; r++){
      int row = wv*64 + st*16 + g*4 + r;
      if(l15 == 0) denP[base + row] = den[st][r];
      #pragma unroll
      for(int dt=0; dt<4; dt++)
        numP[(base + row)*DHEAD + dt*16 + l15] = accO[st][dt][r];
    }
  }
}

__global__ void k_a3v_comb(const float* __restrict__ numP, const float* __restrict__ denP,
                           float* __restrict__ a3v){
  int bidx = blockIdx.x;           // h*256 + m
  int h = bidx >> 8, m = bidx & 255;
  int d = threadIdx.x;
  float s = 0.f, den = 0.f;
  for(int c=0;c<NCHUNK;c++){
    s += numP[(((size_t)h*NCHUNK + c)*NLAND + m)*DHEAD + d];
    den += denP[((size_t)h*NCHUNK + c)*NLAND + m];
  }
  a3v[((size_t)h*NLAND + m)*DHEAD + d] = s / den;
}

// ---------------- residual depthwise conv (k=33), FIR-tiled ----------------
__global__ __launch_bounds__(256) void k_resconv(const float* __restrict__ Vb,
    const float* __restrict__ rw, float* __restrict__ F){
  __shared__ float vs[160][64];
  int n0 = blockIdx.x*128, h = blockIdx.y;
  int t = threadIdx.x;
  const float* vh = Vb + (size_t)h*NPAD*DHEAD;
  #pragma unroll
  for(int i=0;i<10;i++){
    int idx = t + i*256;
    int r = idx >> 4, dq = (idx & 15)*4;
    int n = n0 - 16 + r;
    float4 v = (n>=0 && n<NPAD) ? *(const float4*)(vh + (size_t)n*DHEAD + dq)
                                : make_float4(0.f,0.f,0.f,0.f);
    *(float4*)&vs[r][dq] = v;
  }
  float w[33];
  #pragma unroll
  for(int j=0;j<33;j++) w[j] = rw[h*33+j];
  __syncthreads();
  int d = t & 63, half = t >> 6;
  float acc[32];
  #pragma unroll
  for(int r=0;r<32;r++) acc[r] = 0.f;
  #pragma unroll
  for(int p=0;p<64;p++){
    float vv = vs[half*32 + p][d];
    #pragma unroll
    for(int j=0;j<33;j++){
      int r = p - j;
      if(r >= 0 && r < 32) acc[r] += w[j]*vv;
    }
  }
  #pragma unroll
  for(int r=0;r<32;r++){
    int n = n0 + half*32 + r;
    F[(size_t)n*CDIM + h*DHEAD + d] += acc[r];
  }
}

// ---------------- transpose (weights only) ----------------
__global__ void k_transpose(const float* __restrict__ in, float* __restrict__ out,
                            int R, int C){
  __shared__ float tile[32][33];
  int r0 = blockIdx.x*32, c0 = blockIdx.y*32;
  int tx = threadIdx.x, ty = threadIdx.y;
  #pragma unroll
  for(int r=0;r<4;r++) tile[ty + r*8][tx] = in[(size_t)(r0 + ty + r*8)*C + c0 + tx];
  __syncthreads();
  #pragma unroll
  for(int r=0;r<4;r++) out[(size_t)(c0 + ty + r*8)*R + r0 + tx] = tile[tx][ty + r*8];
}

// ---------------- PPEG direct on row-major [n][c] ----------------
__global__ __launch_bounds__(256) void k_ppeg2(const float* __restrict__ X,
    const float* __restrict__ w7, const float* __restrict__ b7,
    const float* __restrict__ w5, const float* __restrict__ b5,
    const float* __restrict__ w3, const float* __restrict__ b3,
    float* __restrict__ Y){
  __shared__ float patch[484][20];
  int cg = blockIdx.y;
  int ti = blockIdx.x >> 3, tj = blockIdx.x & 7;
  int t = threadIdx.x;
  int i0 = ti*16 - 3, j0 = tj*16 - 3;
  for(int idx = t; idx < 1936; idx += 256){
    int p = idx >> 2, cq = (idx & 3) * 4;
    int gi = i0 + p/22, gj = j0 + p%22;
    float4 v = make_float4(0.f,0.f,0.f,0.f);
    if(gi>=0 && gi<128 && gj>=0 && gj<128)
      v = *(const float4*)(X + (size_t)(gi*128+gj)*CDIM + cg*16 + cq);
    *(float4*)&patch[p][cq] = v;
  }
  int c = t & 15, sg = t >> 4;
  int cglob = cg*16 + c;
  float wr[83];
  #pragma unroll
  for(int k=0;k<49;k++) wr[k] = w7[cglob*49+k];
  #pragma unroll
  for(int k=0;k<25;k++) wr[49+k] = w5[cglob*25+k];
  #pragma unroll
  for(int k=0;k<9;k++)  wr[74+k] = w3[cglob*9+k];
  float bsum = b7[cglob] + b5[cglob] + b3[cglob];
  __syncthreads();
  float acc[16];
  #pragma unroll
  for(int j=0;j<16;j++) acc[j] = patch[(sg+3)*22 + (j+3)][c] + bsum;
  #pragma unroll
  for(int a=0;a<7;a++)
    #pragma unroll
    for(int x=0;x<22;x++){
      float vv = patch[(sg+a)*22 + x][c];
      #pragma unroll
      for(int bq=0;bq<7;bq++){
        int j = x - bq;
        if(j>=0 && j<16) acc[j] += wr[a*7+bq]*vv;
      }
    }
  #pragma unroll
  for(int a=0;a<5;a++)
    #pragma unroll
    for(int x=1;x<21;x++){
      float vv = patch[(sg+a+1)*22 + x][c];
      #pragma unroll
      for(int bq=0;bq<5;bq++){
        int j = x - 1 - bq;
        if(j>=0 && j<16) acc[j] += wr[49+a*5+bq]*vv;
      }
    }
  #pragma unroll
  for(int a=0;a<3;a++)
    #pragma unroll
    for(int x=2;x<20;x++){
      float vv = patch[(sg+a+2)*22 + x][c];
      #pragma unroll
      for(int bq=0;bq<3;bq++){
        int j = x - 2 - bq;
        if(j>=0 && j<16) acc[j] += wr[74+a*3+bq]*vv;
      }
    }
  #pragma unroll
  for(int j=0;j<16;j++)
    Y[(size_t)((ti*16+sg)*128 + tj*16+j)*CDIM + cglob] = acc[j];
}

// ---------------- final LN(row0) + fc2 ----------------
__global__ __launch_bounds__(512) void k_final(const float* __restrict__ A,
    const float* __restrict__ g, const float* __restrict__ b,
    const float* __restrict__ w, const float* __restrict__ bias,
    float* __restrict__ outp){
  __shared__ float red[8];
  int t = threadIdx.x, wv = t >> 6;
  float x = A[t];
  float s = wave_sum(x);
  if((t & 63) == 0) red[wv] = s;
  __syncthreads();
  float mu = 0;
  #pragma unroll
  for(int i=0;i<8;i++) mu += red[i];
  mu *= (1.f/512.f);
  __syncthreads();
  float dx = x - mu;
  s = wave_sum(dx*dx);
  if((t & 63) == 0) red[wv] = s;
  __syncthreads();
  float var = 0;
  #pragma unroll
  for(int i=0;i<8;i++) var += red[i];
  var *= (1.f/512.f);
  float xn = dx * rsqrtf(var + 1e-5f) * g[t] + b[t];
  __syncthreads();
  for(int o=0;o<4;o++){
    s = wave_sum(xn * w[t*4 + o]);
    if((t & 63) == 0) red[wv] = s;
    __syncthreads();
    if(t == 0){
      float r = 0;
      #pragma unroll
      for(int i=0;i<8;i++) r += red[i];
      outp[o] = r + bias[o];
    }
    __syncthreads();
  }
}

extern "C" void kernel_launch(void* const* d_in, const int* in_sizes, int n_in,
                              void* d_out, int out_size, void* d_ws, size_t ws_size,
                              hipStream_t stream) {
  (void)in_sizes; (void)n_in; (void)out_size; (void)ws_size;
  const float* data_x = (const float*)d_in[0];
  const float* fc1_w  = (const float*)d_in[1];
  const float* fc1_b  = (const float*)d_in[2];
  const float* cls_tk = (const float*)d_in[3];
  const float* ng[2]  = {(const float*)d_in[4],  (const float*)d_in[16]};
  const float* nb[2]  = {(const float*)d_in[5],  (const float*)d_in[17]};
  const float* qkvw[2]= {(const float*)d_in[6],  (const float*)d_in[18]};
  const float* outw[2]= {(const float*)d_in[7],  (const float*)d_in[19]};
  const float* outb[2]= {(const float*)d_in[8],  (const float*)d_in[20]};
  const float* resw[2]= {(const float*)d_in[9],  (const float*)d_in[21]};
  const float* w7 = (const float*)d_in[10]; const float* pb7 = (const float*)d_in[11];
  const float* w5 = (const float*)d_in[12]; const float* pb5 = (const float*)d_in[13];
  const float* w3 = (const float*)d_in[14]; const float* pb3 = (const float*)d_in[15];
  const float* norm_g = (const float*)d_in[22];
  const float* norm_b = (const float*)d_in[23];
  const float* fc2_w  = (const float*)d_in[24];
  const float* fc2_b  = (const float*)d_in[25];

  float* ws = (float*)d_ws;
  float* Ab   = ws;                         // 16385*512 (layer-0 h base)
  float* Bb   = Ab + (size_t)TOK*CDIM;      // L0 ln-out; post-ppeg h base
  float* Qb   = Bb + (size_t)NPAD*CDIM;
  float* Kb   = Qb + (size_t)NPAD*CDIM;
  float* Vb   = Kb + (size_t)NPAD*CDIM;
  float* Fb   = Vb + (size_t)NPAD*CDIM;     // L1 ln-out; a3v numP scratch; pre-proj F
  float* qlb  = Fb + (size_t)NPAD*CDIM;     // 8*256*64
  float* klb  = qlb + NHEAD*NLAND*DHEAD;
  float* a2b  = klb + NHEAD*NLAND*DHEAD;    // 8*256*256 f32
  float* z0b  = a2b + NHEAD*NLAND*NLAND;    // zf32 (final z, f32)
  float* z1b  = z0b + NHEAD*NLAND*NLAND;    // carved: zrm1/ztr1 bf16
  float* Xb_  = z1b + NHEAD*NLAND*NLAND;    // carved: Xrm/Xtr bf16
  float* Tb_  = Xb_ + NHEAD*NLAND*NLAND;    // carved: Ttr/Utr bf16
  float* Ub_  = Tb_ + NHEAD*NLAND*NLAND;    // carved: zrm0/ztr0 bf16
  float* a3vb = Ub_ + NHEAD*NLAND*NLAND;    // 8*256*64
  float* w2tb = a3vb + NHEAD*NLAND*DHEAD;   // 8*64*256 (transposed w2)
  float* denP = w2tb + NHEAD*DHEAD*NLAND;   // 8*65*256
  float* hmax = denP + NHEAD*NCHUNK*NLAND;  // 8
  float* scal = hmax + 8;                   // 1
  float* fc1T = scal + 8;                   // 512*1024
  float* qkvT0= fc1T + 512*1024;            // 1536*512
  float* qkvT1= qkvT0 + 1536*512;
  float* outT0= qkvT1 + 1536*512;           // 512*512
  float* outT1= outT0 + 512*512;
  float* a2bfF= outT1 + 512*512;            // 8*65536 bf16 = 262144 floats
  float* qkvT[2] = {qkvT0, qkvT1};
  float* outT[2] = {outT0, outT1};

  const int HB = NHEAD*NLAND*NLAND;         // 524288 shorts per bf16 array
  short* xrm  = (short*)Xb_;  short* xtr  = xrm  + HB;
  short* ttr  = (short*)Tb_;  short* utr  = ttr  + HB;
  short* zrm0 = (short*)Ub_;  short* ztr0 = zrm0 + HB;
  short* zrm1 = (short*)z1b;  short* ztr1 = zrm1 + HB;
  short* a2bf = (short*)a2bfF;

  // weight transposes (WT[n][k])
  k_transpose<<<dim3(32,16), dim3(32,8), 0, stream>>>(fc1_w, fc1T, 1024, 512);
  k_transpose<<<dim3(16,48), dim3(32,8), 0, stream>>>(qkvw[0], qkvT0, 512, 1536);
  k_transpose<<<dim3(16,48), dim3(32,8), 0, stream>>>(qkvw[1], qkvT1, 512, 1536);
  k_transpose<<<dim3(16,16), dim3(32,8), 0, stream>>>(outw[0], outT0, 512, 512);
  k_transpose<<<dim3(16,16), dim3(32,8), 0, stream>>>(outw[1], outT1, 512, 512);

  k_copyrow<<<1, 512, 0, stream>>>(Ab, cls_tk);
  k_gemm_mfma<0><<<dim3(4, 128), 256, 0, stream>>>(data_x, 1024, fc1T, 1024, fc1_b,
                                                   Ab + CDIM, nullptr, nullptr, 16384);
  float* base[2]  = {Ab, Bb};
  float* lnout[2] = {Bb, Fb};
  for(int L=0; L<2; L++){
    k_ln_pad<<<NPAD/4, 256, 0, stream>>>(base[L], ng[L], nb[L], lnout[L]);
    k_gemm_mfma<1><<<dim3(12, 130), 256, 0, stream>>>(lnout[L], CDIM, qkvT[L], CDIM, nullptr,
                                                      Qb, Kb, Vb, NPAD);
    k_landmark<<<NHEAD*NLAND, 64, 0, stream>>>(Qb, qlb);
    k_landmark<<<NHEAD*NLAND, 64, 0, stream>>>(Kb, klb);
    k_a2<<<dim3(4, NHEAD), 256, 0, stream>>>(qlb, klb, a2b, a2bf);
    k_colmax<<<NHEAD, 256, 0, stream>>>(a2b, hmax);
    k_scal<<<1, 64, 0, stream>>>(hmax, scal);
    k_zinit2<<<dim3(256, NHEAD), 256, 0, stream>>>(a2b, scal, zrm0, ztr0);
    k_pinv2<<<8, 512, 0, stream>>>(a2bf, xrm, xtr, ttr, utr,
                                   zrm0, ztr0, zrm1, ztr1, z0b);
    k_a3v_mfma<<<dim3(NHEAD, NCHUNK), 256, 0, stream>>>(qlb, Kb, Vb, Fb, denP);
    k_a3v_comb<<<NHEAD*NLAND, 64, 0, stream>>>(Fb, denP, a3vb);
    k_sgemm2<0,1><<<dim3(1,4,NHEAD), 256, 0, stream>>>(z0b, a3vb, w2tb, 256,64,256,
                                                       65536,16384,16384, 0.f, 1.f);
    k_a1_mfma<<<dim3(130, NHEAD), 256, 0, stream>>>(Qb, klb, w2tb, Fb);
    k_resconv<<<dim3(130, NHEAD), 256, 0, stream>>>(Vb, resw[L], Fb);
    k_gemm_mfma<2><<<dim3(4, 129), 256, 0, stream>>>(Fb + (size_t)PAD0*CDIM, CDIM,
                                                     outT[L], CDIM, outb[L],
                                                     base[L], nullptr, nullptr, TOK);
    if(L == 0){
      k_ppeg2<<<dim3(64, 32), 256, 0, stream>>>(Ab + CDIM, w7, pb7, w5, pb5, w3, pb3,
                                                Bb + CDIM);
      k_copyrow<<<1, 512, 0, stream>>>(Bb, Ab);
    }
  }
  k_final<<<1, 512, 0, stream>>>(Bb, norm_g, norm_b, fc2_w, fc2_b, (float*)d_out);
}